// Round 14
// baseline (809.331 us; speedup 1.0000x reference)
//
#include <hip/hip_runtime.h>
#include <math.h>

// ---------------- problem constants ----------------
constexpr int NN   = 20000;          // nodes
constexpr int NE   = 320000;         // edges  (mean in-degree = 16)
constexpr int ND   = 64;             // node dim
constexpr int ED   = 16;             // edge dim
constexpr int HID  = 256;
constexpr int HEADS= 8;
constexpr int CH   = 32;             // channels per head
constexpr int NB   = 16;             // graphs
constexpr int NL   = 3;              // layers
constexpr int PPG  = 8;              // pool partials per graph
constexpr float NEG_SLOPE = 0.2f;

typedef unsigned short ushort_t;
typedef __attribute__((ext_vector_type(8))) short short8v;   // 8 bf16 (4 VGPRs)
typedef __attribute__((ext_vector_type(4))) float f32x4;     // MFMA acc

// ---------------- workspace layout (float units) ----------------
constexpr size_t OFF_H      = 0;                                // [NN][256] f32
constexpr size_t OFF_HB     = OFF_H      + (size_t)NN*HID;      // [NN][256] bf16
constexpr size_t OFF_EABF   = OFF_HB     + (size_t)NN*HID/2;    // [NE][16] bf16 (CSR order)
constexpr size_t OFF_LOOPBF = OFF_EABF   + (size_t)NE*ED/2;     // [NN][16] bf16
constexpr size_t OFF_HGP    = OFF_LOOPBF + (size_t)NN*ED/2;     // [NB*PPG][256] f32
constexpr size_t OFF_XLB    = OFF_HGP    + (size_t)NB*PPG*HID;  // [NN][256] bf16
constexpr size_t OFF_XRB    = OFF_XLB    + (size_t)NN*HID/2;
constexpr size_t OFF_BT     = OFF_XRB    + (size_t)NN*HID/2;    // [6][256][256] bf16
constexpr size_t OFF_INT    = OFF_BT     + (size_t)6*HID*HID/2;
// int region (indexed in ints from OFF_INT)
constexpr size_t IOFF_DEG    = 0;
constexpr size_t IOFF_ROWOFF = IOFF_DEG    + NN;
constexpr size_t IOFF_CURSOR = IOFF_ROWOFF + NN + 1;
constexpr size_t IOFF_CSRSRC = IOFF_CURSOR + NN;
constexpr size_t IOFF_CSREID = IOFF_CSRSRC + NE;

// ---------------- helpers ----------------
__device__ __forceinline__ ushort_t f2bf(float f) {            // RNE fp32->bf16
  unsigned u = __float_as_uint(f);
  u += 0x7FFFu + ((u >> 16) & 1u);
  return (ushort_t)(u >> 16);
}
__device__ __forceinline__ float bf2f(ushort_t u) {
  return __uint_as_float(((unsigned)u) << 16);
}
__device__ __forceinline__ float4 ld_bf4(const ushort_t* p) {
  ushort4 u = *(const ushort4*)p;
  return make_float4(bf2f(u.x), bf2f(u.y), bf2f(u.z), bf2f(u.w));
}
__device__ __forceinline__ float4 bf4(ushort4 u) {
  return make_float4(bf2f(u.x), bf2f(u.y), bf2f(u.z), bf2f(u.w));
}
// unpack a bf16 pair (packed in uint) to two floats in 2 VALU ops
__device__ __forceinline__ void unpk2(unsigned u, float& lo, float& hi) {
  lo = __uint_as_float(u << 16);
  hi = __uint_as_float(u & 0xffff0000u);
}

// one edge: z = xa + xr + ea@We (f32 weights, 2-op ea unpack), lrelu, att-dot, head reduce
// wv[j] = We[j][c4..c4+3] as float4 (f32, loop-invariant in registers)
__device__ __forceinline__ float edge_logit(const float4 (&wv)[16],
    uint4 ea, uint4 eb, float4 xa, float4 xr4, float4 av) {
  unsigned e[8] = {ea.x, ea.y, ea.z, ea.w, eb.x, eb.y, eb.z, eb.w};
  float z0 = xa.x + xr4.x, z1 = xa.y + xr4.y;
  float z2 = xa.z + xr4.z, z3 = xa.w + xr4.w;
  #pragma unroll
  for (int j2 = 0; j2 < 8; ++j2) {
    float elo, ehi; unpk2(e[j2], elo, ehi);
    float4 w0 = wv[2*j2], w1 = wv[2*j2+1];
    z0 = fmaf(elo, w0.x, z0); z1 = fmaf(elo, w0.y, z1);
    z2 = fmaf(elo, w0.z, z2); z3 = fmaf(elo, w0.w, z3);
    z0 = fmaf(ehi, w1.x, z0); z1 = fmaf(ehi, w1.y, z1);
    z2 = fmaf(ehi, w1.z, z2); z3 = fmaf(ehi, w1.w, z3);
  }
  z0 = z0 > 0.f ? z0 : z0*NEG_SLOPE;
  z1 = z1 > 0.f ? z1 : z1*NEG_SLOPE;
  z2 = z2 > 0.f ? z2 : z2*NEG_SLOPE;
  z3 = z3 > 0.f ? z3 : z3*NEG_SLOPE;
  float p = z0*av.x + z1*av.y + z2*av.z + z3*av.w;
  p += __shfl_xor(p, 1);
  p += __shfl_xor(p, 2);
  p += __shfl_xor(p, 4);
  return p;
}

// ---------------- setup kernels ----------------
// bf16-transposed weights: Bt[mat][n][k] = W[mat][k][n]; mat = l*2+z (z=0:Wl,1:Wr)
__global__ __launch_bounds__(256) void k_wt(const float* __restrict__ Wl,
    const float* __restrict__ Wr, ushort_t* __restrict__ Bt) {
  int i = blockIdx.x*256 + threadIdx.x;
  if (i >= 6*HID*HID) return;
  int mat = i >> 16, rem = i & 65535;
  int k = rem >> 8, n = rem & 255;
  int l = mat >> 1, z = mat & 1;
  const float* W = (z ? Wr : Wl) + (size_t)l*HID*HID;
  Bt[(size_t)mat*HID*HID + (size_t)n*HID + k] = f2bf(W[(size_t)k*HID + n]);
}

// h = x @ node_W + node_b; also writes bf16 mirror hb
__global__ __launch_bounds__(256) void k_node_embed(const float* __restrict__ x,
    const float* __restrict__ W, const float* __restrict__ b,
    float* __restrict__ h, ushort_t* __restrict__ hb) {
  __shared__ float xs[4][ND];
  int n0 = blockIdx.x * 4;
  int tid = threadIdx.x;
  { int r = tid >> 6, j = tid & 63; xs[r][j] = x[(size_t)(n0+r)*ND + j]; }
  __syncthreads();
  int c = tid;
  float a0 = b[c], a1 = b[c], a2 = b[c], a3 = b[c];
  #pragma unroll 8
  for (int j = 0; j < ND; ++j) {
    float w = W[(size_t)j*HID + c];
    a0 += xs[0][j]*w; a1 += xs[1][j]*w; a2 += xs[2][j]*w; a3 += xs[3][j]*w;
  }
  h[(size_t)(n0+0)*HID+c]=a0; h[(size_t)(n0+1)*HID+c]=a1;
  h[(size_t)(n0+2)*HID+c]=a2; h[(size_t)(n0+3)*HID+c]=a3;
  hb[(size_t)(n0+0)*HID+c]=f2bf(a0); hb[(size_t)(n0+1)*HID+c]=f2bf(a1);
  hb[(size_t)(n0+2)*HID+c]=f2bf(a2); hb[(size_t)(n0+3)*HID+c]=f2bf(a3);
}

__global__ __launch_bounds__(256) void k_deg(const int* __restrict__ dst, int* deg) {
  int i = blockIdx.x*256 + threadIdx.x;
  for (; i < NE; i += gridDim.x*256) atomicAdd(&deg[dst[i]], 1);
}

// single-block scan of deg -> row_off (excl prefix) + cursor copy; row_off[NN]=E
__global__ __launch_bounds__(1024) void k_scan(const int* __restrict__ deg,
    int* __restrict__ row_off, int* __restrict__ cursor) {
  __shared__ int sm[1024];
  const int CHK = (NN + 1023) / 1024;   // 20
  int t = threadIdx.x;
  int base = t * CHK;
  int s = 0;
  for (int i = 0; i < CHK; ++i) { int idx = base+i; if (idx < NN) s += deg[idx]; }
  sm[t] = s; __syncthreads();
  for (int off = 1; off < 1024; off <<= 1) {
    int v = (t >= off) ? sm[t-off] : 0;
    __syncthreads();
    sm[t] += v;
    __syncthreads();
  }
  int run = (t == 0) ? 0 : sm[t-1];
  for (int i = 0; i < CHK; ++i) {
    int idx = base+i;
    if (idx < NN) { row_off[idx] = run; cursor[idx] = run; run += deg[idx]; }
  }
  if (t == 1023) row_off[NN] = sm[1023];
}

__global__ __launch_bounds__(256) void k_fill(const int* __restrict__ src, const int* __restrict__ dst,
    int* cursor, int* __restrict__ csr_src, int* __restrict__ csr_eid) {
  int e = blockIdx.x*256 + threadIdx.x;
  for (; e < NE; e += gridDim.x*256) {
    int pos = atomicAdd(&cursor[dst[e]], 1);
    csr_src[pos] = src[e];
    csr_eid[pos] = e;
  }
}

// fused: ea rows (edge_attr @ edge_W + edge_b) in CSR order (bf16) + per-node mean (bf16)
__global__ __launch_bounds__(256) void k_edge_prep(const float* __restrict__ edge_attr,
    const float* __restrict__ edge_W, const float* __restrict__ edge_b,
    const int* __restrict__ row_off, const int* __restrict__ csr_eid,
    ushort_t* __restrict__ ea_bf, ushort_t* __restrict__ loopea_bf) {
  int lane = threadIdx.x & 63;
  int n = (blockIdx.x*256 + threadIdx.x) >> 6;
  if (n >= NN) return;
  int e4 = lane >> 4, c = lane & 15;
  float Wc[16];
  #pragma unroll
  for (int j = 0; j < 16; ++j) Wc[j] = edge_W[j*ED + c];
  float bc = edge_b[c];
  int b0 = row_off[n], b1 = row_off[n+1];
  float sum = 0.f;
  for (int kb = b0; kb < b1; kb += 4) {
    int k = kb + e4;
    bool ok = (k < b1);
    int eid = ok ? csr_eid[k] : 0;
    float avv = ok ? edge_attr[(size_t)eid*ED + c] : 0.f;
    float r = bc;
    #pragma unroll
    for (int j = 0; j < 16; ++j) {
      float aj = __shfl(avv, (e4 << 4) + j);
      r += aj * Wc[j];
    }
    if (ok) { ea_bf[(size_t)k*ED + c] = f2bf(r); sum += r; }
  }
  sum += __shfl_xor(sum, 16);
  sum += __shfl_xor(sum, 32);
  if (lane < 16) {
    int dg = b1 - b0;
    loopea_bf[(size_t)n*ED + c] = f2bf(sum / (float)(dg > 1 ? dg : 1));
  }
}

// ---------------- bf16 MFMA dual GEMM: BOTH matrices in one block ----------------
// 512 threads = 8 waves; waves 0-3 -> Wl cols, waves 4-7 -> Wr cols; shared A tile.
__global__ __launch_bounds__(512) void k_gemm_bf16(const ushort_t* __restrict__ hb,
    const ushort_t* __restrict__ Bt,
    const float* __restrict__ bias0, const float* __restrict__ bias1,
    ushort_t* __restrict__ C0, ushort_t* __restrict__ C1, int M) {
  __shared__ ushort_t As[64][HID + 8];       // 64 x 264 bf16 = 33.8 KB
  int tid = threadIdx.x;
  int w = tid >> 6;                 // 0..7
  int z = w >> 2;                   // matrix select
  int wsub = w & 3;                 // 64-col group within matrix
  int lane = tid & 63, l15 = lane & 15, kg = lane >> 4;
  int m0 = blockIdx.x * 64;
  const ushort_t* B = Bt + (size_t)z*HID*HID;
  const float* bias = z ? bias1 : bias0;
  ushort_t* C       = z ? C1 : C0;
  // stage full A tile once (shared by both matrices): 8 threads/row x 32 cols
  {
    int r = tid >> 3, cchunk = (tid & 7) * 32;
    int gr = m0 + r; if (gr >= M) gr = M - 1;
    const float4* srcp = (const float4*)(hb + (size_t)gr*HID + cchunk);
    float4 t0 = srcp[0], t1 = srcp[1], t2 = srcp[2], t3 = srcp[3];
    *(float4*)&As[r][cchunk+0]  = t0;
    *(float4*)&As[r][cchunk+8]  = t1;
    *(float4*)&As[r][cchunk+16] = t2;
    *(float4*)&As[r][cchunk+24] = t3;
  }
  f32x4 acc[4][4];
  #pragma unroll
  for (int mi = 0; mi < 4; ++mi)
    #pragma unroll
    for (int ni = 0; ni < 4; ++ni)
      acc[mi][ni] = (f32x4){0.f,0.f,0.f,0.f};
  // B pipeline: prefetch k0=0 fragments while A staging settles
  const ushort_t* Bw = B + (size_t)(wsub*64 + l15)*HID + kg*8;   // + ni*16*HID + k0
  short8v bn[4];
  #pragma unroll
  for (int ni = 0; ni < 4; ++ni)
    bn[ni] = *(const short8v*)(Bw + (size_t)ni*16*HID);
  __syncthreads();
  for (int k0 = 0; k0 < HID; k0 += 32) {
    short8v a[4], b[4];
    #pragma unroll
    for (int ni = 0; ni < 4; ++ni) b[ni] = bn[ni];
    if (k0 + 32 < HID) {
      #pragma unroll
      for (int ni = 0; ni < 4; ++ni)
        bn[ni] = *(const short8v*)(Bw + (size_t)ni*16*HID + k0 + 32);
    }
    #pragma unroll
    for (int mi = 0; mi < 4; ++mi)
      a[mi] = *(const short8v*)&As[mi*16 + l15][k0 + kg*8];
    #pragma unroll
    for (int mi = 0; mi < 4; ++mi)
      #pragma unroll
      for (int ni = 0; ni < 4; ++ni)
        acc[mi][ni] = __builtin_amdgcn_mfma_f32_16x16x32_bf16(a[mi], b[ni], acc[mi][ni], 0, 0, 0);
  }
  // epilogue: D col = lane&15 (n-dim), row = (lane>>4)*4 + r (m-dim)
  #pragma unroll
  for (int ni = 0; ni < 4; ++ni) {
    int col = wsub*64 + ni*16 + l15;
    float bs = bias[col];
    #pragma unroll
    for (int mi = 0; mi < 4; ++mi) {
      #pragma unroll
      for (int r = 0; r < 4; ++r) {
        int row = m0 + mi*16 + kg*4 + r;
        if (row < M) C[(size_t)row*HID + col] = f2bf(acc[mi][ni][r] + bs);
      }
    }
  }
}

// ---- fused GATv2 attention: 1 wave/node, 4-edge unroll, f32-weight eemb with
// 2-op bf16 ea unpack, X+EA prefetch, direct exp accumulation ----
__global__ __launch_bounds__(256) void k_gat_fused(
    const ushort_t* __restrict__ xlb, const ushort_t* __restrict__ xrb,
    const ushort_t* __restrict__ ea_bf, const ushort_t* __restrict__ loopea_bf,
    const int* __restrict__ row_off, const int* __restrict__ csr_src,
    const float* __restrict__ We, const float* __restrict__ att,
    const float* __restrict__ bias, float* __restrict__ h, ushort_t* __restrict__ hb) {
  int lane = threadIdx.x & 63;
  int n = (blockIdx.x*256 + threadIdx.x) >> 6;
  if (n >= NN) return;
  int c4 = lane*4;
  int hh = lane >> 3;
  // per-lane f32 We columns: wv[j] = We[j][c4..c4+3]  (64 VGPR, loop-invariant)
  float4 wv[16];
  #pragma unroll
  for (int j = 0; j < 16; ++j) wv[j] = *(const float4*)(We + (size_t)j*HID + c4);
  float4 av  = *(const float4*)(att + hh*CH + (lane&7)*4);
  float4 xr4 = ld_bf4(xrb + (size_t)n*HID + c4);
  float4 xls = ld_bf4(xlb + (size_t)n*HID + c4);

  // self-loop: direct exp (no max subtraction; logits are small)
  float denom; float4 acc;
  {
    const uint4* lp = (const uint4*)(loopea_bf + (size_t)n*ED);
    float ps = edge_logit(wv, lp[0], lp[1], xls, xr4, av);
    float es = __expf(ps);
    denom = es;
    acc = make_float4(es*xls.x, es*xls.y, es*xls.z, es*xls.w);
  }

  int b0 = row_off[n], b1 = row_off[n+1];
  if (b0 < b1) {
    int last = b1 - 1;
    ushort4 X0, X1, X2, X3;
    uint4 E0, E1, E2, E3, E4, E5, E6, E7;
    {
      int k1 = b0+1 < last ? b0+1 : last;
      int k2 = b0+2 < last ? b0+2 : last;
      int k3 = b0+3 < last ? b0+3 : last;
      X0 = *(const ushort4*)(xlb + (size_t)csr_src[b0]*HID + c4);
      X1 = *(const ushort4*)(xlb + (size_t)csr_src[k1]*HID + c4);
      X2 = *(const ushort4*)(xlb + (size_t)csr_src[k2]*HID + c4);
      X3 = *(const ushort4*)(xlb + (size_t)csr_src[k3]*HID + c4);
      const uint4* ep = (const uint4*)(ea_bf + (size_t)b0*ED);   // reads 4 rows; overrun past b1 is masked
      E0 = ep[0]; E1 = ep[1]; E2 = ep[2]; E3 = ep[3];
      E4 = ep[4]; E5 = ep[5]; E6 = ep[6]; E7 = ep[7];
    }
    for (int kb = b0; kb < b1; kb += 4) {
      int rem = b1 - kb;
      ushort4 A0 = X0, A1 = X1, A2 = X2, A3 = X3;
      uint4 F0 = E0, F1 = E1, F2 = E2, F3 = E3;
      uint4 F4 = E4, F5 = E5, F6 = E6, F7 = E7;
      if (kb + 4 < b1) {
        int k0 = kb+4;
        int k1 = kb+5 < last ? kb+5 : last;
        int k2 = kb+6 < last ? kb+6 : last;
        int k3 = kb+7 < last ? kb+7 : last;
        X0 = *(const ushort4*)(xlb + (size_t)csr_src[k0]*HID + c4);
        X1 = *(const ushort4*)(xlb + (size_t)csr_src[k1]*HID + c4);
        X2 = *(const ushort4*)(xlb + (size_t)csr_src[k2]*HID + c4);
        X3 = *(const ushort4*)(xlb + (size_t)csr_src[k3]*HID + c4);
        const uint4* ep2 = (const uint4*)(ea_bf + (size_t)(kb+4)*ED);
        E0 = ep2[0]; E1 = ep2[1]; E2 = ep2[2]; E3 = ep2[3];
        E4 = ep2[4]; E5 = ep2[5]; E6 = ep2[6]; E7 = ep2[7];
      }
      float4 xa = bf4(A0), xb_ = bf4(A1), xc = bf4(A2), xd = bf4(A3);
      float p0 = edge_logit(wv, F0, F1, xa,  xr4, av);
      float p1 = edge_logit(wv, F2, F3, xb_, xr4, av);
      float p2 = edge_logit(wv, F4, F5, xc,  xr4, av);
      float p3 = edge_logit(wv, F6, F7, xd,  xr4, av);
      p1 = (rem > 1) ? p1 : -3.0e38f;   // __expf(-3e38) == 0 -> masked
      p2 = (rem > 2) ? p2 : -3.0e38f;
      p3 = (rem > 3) ? p3 : -3.0e38f;
      float e0 = __expf(p0), e1 = __expf(p1);
      float e2 = __expf(p2), e3 = __expf(p3);
      denom += ((e0+e1) + (e2+e3));
      acc.x += ((e0*xa.x + e1*xb_.x) + (e2*xc.x + e3*xd.x));
      acc.y += ((e0*xa.y + e1*xb_.y) + (e2*xc.y + e3*xd.y));
      acc.z += ((e0*xa.z + e1*xb_.z) + (e2*xc.z + e3*xd.z));
      acc.w += ((e0*xa.w + e1*xb_.w) + (e2*xc.w + e3*xd.w));
    }
  }
  float inv = 1.f / denom;
  float* hp = h + (size_t)n*HID + c4;
  float4 hv = *(const float4*)hp;
  float4 b4 = *(const float4*)(bias + c4);
  hv.x += acc.x*inv + b4.x;
  hv.y += acc.y*inv + b4.y;
  hv.z += acc.z*inv + b4.z;
  hv.w += acc.w*inv + b4.w;
  *(float4*)hp = hv;
  ushort4 hbv = make_ushort4(f2bf(hv.x), f2bf(hv.y), f2bf(hv.z), f2bf(hv.w));
  *(ushort4*)(hb + (size_t)n*HID + c4) = hbv;
}

// pool partials: block (g,q) sums its slice of graph g's rows; no atomics
__global__ __launch_bounds__(256) void k_pool_part(const float* __restrict__ h,
    const int* __restrict__ batch, float* __restrict__ hgp) {
  int g = blockIdx.x >> 3, q = blockIdx.x & 7;
  int c = threadIdx.x;
  int lo = 0, hi = NN;
  while (lo < hi) { int mid = (lo+hi) >> 1; if (batch[mid] <  g) lo = mid+1; else hi = mid; }
  int n0 = lo;
  lo = 0; hi = NN;
  while (lo < hi) { int mid = (lo+hi) >> 1; if (batch[mid] <= g) lo = mid+1; else hi = mid; }
  int n1 = lo;
  int len = n1 - n0;
  int a = n0 + (int)(( (long long)len *  q   ) / PPG);
  int b = n0 + (int)(( (long long)len * (q+1)) / PPG);
  float acc = 0.f;
  for (int n = a; n < b; ++n) acc += h[(size_t)n*HID + c];
  hgp[(size_t)blockIdx.x*HID + c] = acc;
}

// out = gelu(mean @ W1 + b1) @ W2 + b2 ; one block per graph
__global__ __launch_bounds__(256) void k_mlp(const float* __restrict__ hgp,
    const int* __restrict__ batch,
    const float* __restrict__ W1, const float* __restrict__ b1,
    const float* __restrict__ W2, const float* __restrict__ b2, float* __restrict__ out) {
  __shared__ float row[HID];
  __shared__ float zrow[HID];
  int g = blockIdx.x, c = threadIdx.x;
  int lo = 0, hi = NN;
  while (lo < hi) { int mid = (lo+hi) >> 1; if (batch[mid] <  g) lo = mid+1; else hi = mid; }
  int n0 = lo;
  lo = 0; hi = NN;
  while (lo < hi) { int mid = (lo+hi) >> 1; if (batch[mid] <= g) lo = mid+1; else hi = mid; }
  float cn = (float)(lo - n0); if (cn < 1.f) cn = 1.f;
  float s = 0.f;
  #pragma unroll
  for (int q = 0; q < PPG; ++q) s += hgp[(size_t)(g*PPG + q)*HID + c];
  row[c] = s / cn;
  __syncthreads();
  float acc = b1[c];
  for (int j = 0; j < HID; ++j) acc += row[j] * W1[(size_t)j*HID + c];
  float ge = 0.5f * acc * (1.f + erff(acc * 0.70710678118654752440f));
  zrow[c] = ge;
  __syncthreads();
  float acc2 = b2[c];
  for (int j = 0; j < HID; ++j) acc2 += zrow[j] * W2[(size_t)j*HID + c];
  out[(size_t)g*HID + c] = acc2;
}

extern "C" void kernel_launch(void* const* d_in, const int* in_sizes, int n_in,
                              void* d_out, int out_size, void* d_ws, size_t ws_size,
                              hipStream_t stream) {
  const float* x         = (const float*)d_in[0];
  const int*   edge_index= (const int*)  d_in[1];
  const float* edge_attr = (const float*)d_in[2];
  const int*   batch     = (const int*)  d_in[3];
  const float* node_W    = (const float*)d_in[4];
  const float* node_b    = (const float*)d_in[5];
  const float* edge_W    = (const float*)d_in[6];
  const float* edge_b    = (const float*)d_in[7];
  const float* Wl        = (const float*)d_in[8];
  const float* bl        = (const float*)d_in[9];
  const float* Wr        = (const float*)d_in[10];
  const float* br        = (const float*)d_in[11];
  const float* We        = (const float*)d_in[12];
  const float* att       = (const float*)d_in[13];
  const float* conv_bias = (const float*)d_in[14];
  const float* W1        = (const float*)d_in[15];
  const float* b1        = (const float*)d_in[16];
  const float* W2        = (const float*)d_in[17];
  const float* b2        = (const float*)d_in[18];
  const int* srcp = edge_index;
  const int* dstp = edge_index + NE;

  float* ws = (float*)d_ws;
  float* h          = ws + OFF_H;
  ushort_t* hb      = (ushort_t*)(ws + OFF_HB);
  ushort_t* ea_bf   = (ushort_t*)(ws + OFF_EABF);
  ushort_t* loop_bf = (ushort_t*)(ws + OFF_LOOPBF);
  float* hgp        = ws + OFF_HGP;
  ushort_t* xlb     = (ushort_t*)(ws + OFF_XLB);
  ushort_t* xrb     = (ushort_t*)(ws + OFF_XRB);
  ushort_t* Bt      = (ushort_t*)(ws + OFF_BT);
  int* ib       = (int*)(ws + OFF_INT);
  int* deg      = ib + IOFF_DEG;
  int* row_off  = ib + IOFF_ROWOFF;
  int* cursor   = ib + IOFF_CURSOR;
  int* csr_src  = ib + IOFF_CSRSRC;
  int* csr_eid  = ib + IOFF_CSREID;

  hipMemsetAsync(deg, 0, NN*sizeof(int), stream);
  k_wt<<<(6*HID*HID + 255)/256, 256, 0, stream>>>(Wl, Wr, Bt);
  k_node_embed<<<NN/4, 256, 0, stream>>>(x, node_W, node_b, h, hb);
  k_deg<<<1250, 256, 0, stream>>>(dstp, deg);
  k_scan<<<1, 1024, 0, stream>>>(deg, row_off, cursor);
  k_fill<<<1250, 256, 0, stream>>>(srcp, dstp, cursor, csr_src, csr_eid);
  k_edge_prep<<<(NN*64 + 255)/256, 256, 0, stream>>>(edge_attr, edge_W, edge_b,
      row_off, csr_eid, ea_bf, loop_bf);

  for (int l = 0; l < NL; ++l) {
    k_gemm_bf16<<<(NN + 63)/64, 512, 0, stream>>>(hb, Bt + (size_t)l*2*HID*HID,
        bl + (size_t)l*HID, br + (size_t)l*HID, xlb, xrb, NN);
    k_gat_fused<<<(NN*64 + 255)/256, 256, 0, stream>>>(xlb, xrb, ea_bf, loop_bf,
        row_off, csr_src,
        We + (size_t)l*ED*HID,
        att + (size_t)l*HEADS*CH, conv_bias + (size_t)l*HID, h, hb);
  }

  k_pool_part<<<NB*PPG, 256, 0, stream>>>(h, batch, hgp);
  k_mlp<<<NB, 256, 0, stream>>>(hgp, batch, W1, b1, W2, b2, (float*)d_out);
}

// Round 15
// 549.740 us; speedup vs baseline: 1.4722x; 1.4722x over previous
//
#include <hip/hip_runtime.h>
#include <math.h>

// ---------------- problem constants ----------------
constexpr int NN   = 20000;          // nodes
constexpr int NE   = 320000;         // edges  (mean in-degree = 16)
constexpr int ND   = 64;             // node dim
constexpr int ED   = 16;             // edge dim
constexpr int HID  = 256;
constexpr int HEADS= 8;
constexpr int CH   = 32;             // channels per head
constexpr int NB   = 16;             // graphs
constexpr int NL   = 3;              // layers
constexpr int PPG  = 8;              // pool partials per graph
constexpr int GAT_BLOCKS = 1536;     // persistent waves: 6144 ≈ 24 waves/CU (VGPR cap)
constexpr float NEG_SLOPE = 0.2f;

typedef unsigned short ushort_t;
typedef __attribute__((ext_vector_type(8))) short short8v;   // 8 bf16 (4 VGPRs)
typedef __attribute__((ext_vector_type(4))) float f32x4;     // MFMA acc

#if __has_builtin(__builtin_amdgcn_fdot2_f32_bf16)
  #define HAVE_DOT2 1
  typedef __bf16 bf16x2v __attribute__((ext_vector_type(2)));
#endif

// ---------------- workspace layout (float units) ----------------
constexpr size_t OFF_H      = 0;                                // [NN][256] f32
constexpr size_t OFF_HB     = OFF_H      + (size_t)NN*HID;      // [NN][256] bf16
constexpr size_t OFF_EABF   = OFF_HB     + (size_t)NN*HID/2;    // [NE][16] bf16 (CSR order)
constexpr size_t OFF_LOOPBF = OFF_EABF   + (size_t)NE*ED/2;     // [NN][16] bf16
constexpr size_t OFF_HGP    = OFF_LOOPBF + (size_t)NN*ED/2;     // [NB*PPG][256] f32
constexpr size_t OFF_XLB    = OFF_HGP    + (size_t)NB*PPG*HID;  // [NN][256] bf16
constexpr size_t OFF_XRB    = OFF_XLB    + (size_t)NN*HID/2;
constexpr size_t OFF_BT     = OFF_XRB    + (size_t)NN*HID/2;    // [6][256][256] bf16
constexpr size_t OFF_WEPK   = OFF_BT     + (size_t)6*HID*HID/2; // [NL][256][8] bf16-pairs (uint)
constexpr size_t OFF_INT    = OFF_WEPK   + (size_t)NL*HID*8;
// int region (indexed in ints from OFF_INT)
constexpr size_t IOFF_DEG    = 0;
constexpr size_t IOFF_ROWOFF = IOFF_DEG    + NN;
constexpr size_t IOFF_CURSOR = IOFF_ROWOFF + NN + 1;
constexpr size_t IOFF_CSRSRC = IOFF_CURSOR + NN;
constexpr size_t IOFF_CSREID = IOFF_CSRSRC + NE;

// ---------------- helpers ----------------
__device__ __forceinline__ ushort_t f2bf(float f) {            // RNE fp32->bf16
  unsigned u = __float_as_uint(f);
  u += 0x7FFFu + ((u >> 16) & 1u);
  return (ushort_t)(u >> 16);
}
__device__ __forceinline__ float bf2f(ushort_t u) {
  return __uint_as_float(((unsigned)u) << 16);
}
__device__ __forceinline__ float4 ld_bf4(const ushort_t* p) {
  ushort4 u = *(const ushort4*)p;
  return make_float4(bf2f(u.x), bf2f(u.y), bf2f(u.z), bf2f(u.w));
}
__device__ __forceinline__ float4 bf4(ushort4 u) {
  return make_float4(bf2f(u.x), bf2f(u.y), bf2f(u.z), bf2f(u.w));
}

// d = dot(bf16pair w, bf16pair e) + c
__device__ __forceinline__ float dot2bf(unsigned w, unsigned e, float c) {
#ifdef HAVE_DOT2
  return __builtin_amdgcn_fdot2_f32_bf16(__builtin_bit_cast(bf16x2v, w),
                                         __builtin_bit_cast(bf16x2v, e), c, false);
#else
  float w0 = bf2f((ushort_t)(w & 0xffff)), w1 = bf2f((ushort_t)(w >> 16));
  float e0 = bf2f((ushort_t)(e & 0xffff)), e1 = bf2f((ushort_t)(e >> 16));
  return c + w0*e0 + w1*e1;
#endif
}

// one edge: z = xa + xr + ea@We (dot2), lrelu, att-dot, 8-lane head reduce
__device__ __forceinline__ float edge_logit(const unsigned (&wpk)[4][8],
    uint4 ea, uint4 eb, float4 xa, float4 xr4, float4 av) {
  unsigned e[8] = {ea.x, ea.y, ea.z, ea.w, eb.x, eb.y, eb.z, eb.w};
  float z0 = xa.x + xr4.x, z1 = xa.y + xr4.y;
  float z2 = xa.z + xr4.z, z3 = xa.w + xr4.w;
  #pragma unroll
  for (int j = 0; j < 8; ++j) {
    z0 = dot2bf(wpk[0][j], e[j], z0);
    z1 = dot2bf(wpk[1][j], e[j], z1);
    z2 = dot2bf(wpk[2][j], e[j], z2);
    z3 = dot2bf(wpk[3][j], e[j], z3);
  }
  z0 = z0 > 0.f ? z0 : z0*NEG_SLOPE;
  z1 = z1 > 0.f ? z1 : z1*NEG_SLOPE;
  z2 = z2 > 0.f ? z2 : z2*NEG_SLOPE;
  z3 = z3 > 0.f ? z3 : z3*NEG_SLOPE;
  float p = z0*av.x + z1*av.y + z2*av.z + z3*av.w;
  p += __shfl_xor(p, 1);
  p += __shfl_xor(p, 2);
  p += __shfl_xor(p, 4);
  return p;
}

// ---------------- setup kernels ----------------
// bf16-transposed weights: Bt[mat][n][k] = W[mat][k][n]; mat = l*2+z (z=0:Wl,1:Wr)
__global__ __launch_bounds__(256) void k_wt(const float* __restrict__ Wl,
    const float* __restrict__ Wr, ushort_t* __restrict__ Bt) {
  int i = blockIdx.x*256 + threadIdx.x;
  if (i >= 6*HID*HID) return;
  int mat = i >> 16, rem = i & 65535;
  int k = rem >> 8, n = rem & 255;
  int l = mat >> 1, z = mat & 1;
  const float* W = (z ? Wr : Wl) + (size_t)l*HID*HID;
  Bt[(size_t)mat*HID*HID + (size_t)n*HID + k] = f2bf(W[(size_t)k*HID + n]);
}

// We packed as bf16 pairs: Wepk[l][c][j2] = (We[l][2j2][c], We[l][2j2+1][c])
__global__ __launch_bounds__(256) void k_wepk(const float* __restrict__ We,
    unsigned* __restrict__ Wepk) {
  int i = blockIdx.x*256 + threadIdx.x;
  if (i >= NL*HID*8) return;
  int l = i / (HID*8), rem = i % (HID*8);
  int c = rem >> 3, j2 = rem & 7;
  const float* W = We + (size_t)l*ED*HID;
  unsigned lo = f2bf(W[(size_t)(2*j2)*HID + c]);
  unsigned hi = f2bf(W[(size_t)(2*j2+1)*HID + c]);
  Wepk[i] = lo | (hi << 16);
}

// h = x @ node_W + node_b; also writes bf16 mirror hb
__global__ __launch_bounds__(256) void k_node_embed(const float* __restrict__ x,
    const float* __restrict__ W, const float* __restrict__ b,
    float* __restrict__ h, ushort_t* __restrict__ hb) {
  __shared__ float xs[4][ND];
  int n0 = blockIdx.x * 4;
  int tid = threadIdx.x;
  { int r = tid >> 6, j = tid & 63; xs[r][j] = x[(size_t)(n0+r)*ND + j]; }
  __syncthreads();
  int c = tid;
  float a0 = b[c], a1 = b[c], a2 = b[c], a3 = b[c];
  #pragma unroll 8
  for (int j = 0; j < ND; ++j) {
    float w = W[(size_t)j*HID + c];
    a0 += xs[0][j]*w; a1 += xs[1][j]*w; a2 += xs[2][j]*w; a3 += xs[3][j]*w;
  }
  h[(size_t)(n0+0)*HID+c]=a0; h[(size_t)(n0+1)*HID+c]=a1;
  h[(size_t)(n0+2)*HID+c]=a2; h[(size_t)(n0+3)*HID+c]=a3;
  hb[(size_t)(n0+0)*HID+c]=f2bf(a0); hb[(size_t)(n0+1)*HID+c]=f2bf(a1);
  hb[(size_t)(n0+2)*HID+c]=f2bf(a2); hb[(size_t)(n0+3)*HID+c]=f2bf(a3);
}

__global__ __launch_bounds__(256) void k_deg(const int* __restrict__ dst, int* deg) {
  int i = blockIdx.x*256 + threadIdx.x;
  for (; i < NE; i += gridDim.x*256) atomicAdd(&deg[dst[i]], 1);
}

// single-block scan of deg -> row_off (excl prefix) + cursor copy; row_off[NN]=E
__global__ __launch_bounds__(1024) void k_scan(const int* __restrict__ deg,
    int* __restrict__ row_off, int* __restrict__ cursor) {
  __shared__ int sm[1024];
  const int CHK = (NN + 1023) / 1024;   // 20
  int t = threadIdx.x;
  int base = t * CHK;
  int s = 0;
  for (int i = 0; i < CHK; ++i) { int idx = base+i; if (idx < NN) s += deg[idx]; }
  sm[t] = s; __syncthreads();
  for (int off = 1; off < 1024; off <<= 1) {
    int v = (t >= off) ? sm[t-off] : 0;
    __syncthreads();
    sm[t] += v;
    __syncthreads();
  }
  int run = (t == 0) ? 0 : sm[t-1];
  for (int i = 0; i < CHK; ++i) {
    int idx = base+i;
    if (idx < NN) { row_off[idx] = run; cursor[idx] = run; run += deg[idx]; }
  }
  if (t == 1023) row_off[NN] = sm[1023];
}

__global__ __launch_bounds__(256) void k_fill(const int* __restrict__ src, const int* __restrict__ dst,
    int* cursor, int* __restrict__ csr_src, int* __restrict__ csr_eid) {
  int e = blockIdx.x*256 + threadIdx.x;
  for (; e < NE; e += gridDim.x*256) {
    int pos = atomicAdd(&cursor[dst[e]], 1);
    csr_src[pos] = src[e];
    csr_eid[pos] = e;
  }
}

// fused: ea rows (edge_attr @ edge_W + edge_b) in CSR order (bf16) + per-node mean (bf16)
__global__ __launch_bounds__(256) void k_edge_prep(const float* __restrict__ edge_attr,
    const float* __restrict__ edge_W, const float* __restrict__ edge_b,
    const int* __restrict__ row_off, const int* __restrict__ csr_eid,
    ushort_t* __restrict__ ea_bf, ushort_t* __restrict__ loopea_bf) {
  int lane = threadIdx.x & 63;
  int n = (blockIdx.x*256 + threadIdx.x) >> 6;
  if (n >= NN) return;
  int e4 = lane >> 4, c = lane & 15;
  float Wc[16];
  #pragma unroll
  for (int j = 0; j < 16; ++j) Wc[j] = edge_W[j*ED + c];
  float bc = edge_b[c];
  int b0 = row_off[n], b1 = row_off[n+1];
  float sum = 0.f;
  for (int kb = b0; kb < b1; kb += 4) {
    int k = kb + e4;
    bool ok = (k < b1);
    int eid = ok ? csr_eid[k] : 0;
    float avv = ok ? edge_attr[(size_t)eid*ED + c] : 0.f;
    float r = bc;
    #pragma unroll
    for (int j = 0; j < 16; ++j) {
      float aj = __shfl(avv, (e4 << 4) + j);
      r += aj * Wc[j];
    }
    if (ok) { ea_bf[(size_t)k*ED + c] = f2bf(r); sum += r; }
  }
  sum += __shfl_xor(sum, 16);
  sum += __shfl_xor(sum, 32);
  if (lane < 16) {
    int dg = b1 - b0;
    loopea_bf[(size_t)n*ED + c] = f2bf(sum / (float)(dg > 1 ? dg : 1));
  }
}

// ---------------- bf16 MFMA dual GEMM: BOTH matrices in one block ----------------
__global__ __launch_bounds__(512) void k_gemm_bf16(const ushort_t* __restrict__ hb,
    const ushort_t* __restrict__ Bt,
    const float* __restrict__ bias0, const float* __restrict__ bias1,
    ushort_t* __restrict__ C0, ushort_t* __restrict__ C1, int M) {
  __shared__ ushort_t As[64][HID + 8];       // 64 x 264 bf16 = 33.8 KB
  int tid = threadIdx.x;
  int w = tid >> 6;                 // 0..7
  int z = w >> 2;                   // matrix select
  int wsub = w & 3;                 // 64-col group within matrix
  int lane = tid & 63, l15 = lane & 15, kg = lane >> 4;
  int m0 = blockIdx.x * 64;
  const ushort_t* B = Bt + (size_t)z*HID*HID;
  const float* bias = z ? bias1 : bias0;
  ushort_t* C       = z ? C1 : C0;
  // stage full A tile once (shared by both matrices): 8 threads/row x 32 cols
  {
    int r = tid >> 3, cchunk = (tid & 7) * 32;
    int gr = m0 + r; if (gr >= M) gr = M - 1;
    const float4* srcp = (const float4*)(hb + (size_t)gr*HID + cchunk);
    float4 t0 = srcp[0], t1 = srcp[1], t2 = srcp[2], t3 = srcp[3];
    *(float4*)&As[r][cchunk+0]  = t0;
    *(float4*)&As[r][cchunk+8]  = t1;
    *(float4*)&As[r][cchunk+16] = t2;
    *(float4*)&As[r][cchunk+24] = t3;
  }
  f32x4 acc[4][4];
  #pragma unroll
  for (int mi = 0; mi < 4; ++mi)
    #pragma unroll
    for (int ni = 0; ni < 4; ++ni)
      acc[mi][ni] = (f32x4){0.f,0.f,0.f,0.f};
  // B pipeline: prefetch k0=0 fragments while A staging settles
  const ushort_t* Bw = B + (size_t)(wsub*64 + l15)*HID + kg*8;   // + ni*16*HID + k0
  short8v bn[4];
  #pragma unroll
  for (int ni = 0; ni < 4; ++ni)
    bn[ni] = *(const short8v*)(Bw + (size_t)ni*16*HID);
  __syncthreads();
  for (int k0 = 0; k0 < HID; k0 += 32) {
    short8v a[4], b[4];
    #pragma unroll
    for (int ni = 0; ni < 4; ++ni) b[ni] = bn[ni];
    if (k0 + 32 < HID) {
      #pragma unroll
      for (int ni = 0; ni < 4; ++ni)
        bn[ni] = *(const short8v*)(Bw + (size_t)ni*16*HID + k0 + 32);
    }
    #pragma unroll
    for (int mi = 0; mi < 4; ++mi)
      a[mi] = *(const short8v*)&As[mi*16 + l15][k0 + kg*8];
    #pragma unroll
    for (int mi = 0; mi < 4; ++mi)
      #pragma unroll
      for (int ni = 0; ni < 4; ++ni)
        acc[mi][ni] = __builtin_amdgcn_mfma_f32_16x16x32_bf16(a[mi], b[ni], acc[mi][ni], 0, 0, 0);
  }
  // epilogue: D col = lane&15 (n-dim), row = (lane>>4)*4 + r (m-dim)
  #pragma unroll
  for (int ni = 0; ni < 4; ++ni) {
    int col = wsub*64 + ni*16 + l15;
    float bs = bias[col];
    #pragma unroll
    for (int mi = 0; mi < 4; ++mi) {
      #pragma unroll
      for (int r = 0; r < 4; ++r) {
        int row = m0 + mi*16 + kg*4 + r;
        if (row < M) C[(size_t)row*HID + col] = f2bf(acc[mi][ni][r] + bs);
      }
    }
  }
}

// ---- fused GATv2 attention: PERSISTENT grid-stride waves (R13 body per node) ----
__global__ __launch_bounds__(256) void k_gat_fused(
    const ushort_t* __restrict__ xlb, const ushort_t* __restrict__ xrb,
    const ushort_t* __restrict__ ea_bf, const ushort_t* __restrict__ loopea_bf,
    const int* __restrict__ row_off, const int* __restrict__ csr_src,
    const unsigned* __restrict__ Wepk, const float* __restrict__ att,
    const float* __restrict__ bias, float* __restrict__ h, ushort_t* __restrict__ hb) {
  int lane = threadIdx.x & 63;
  int wid = (blockIdx.x*256 + threadIdx.x) >> 6;
  const int NW = GAT_BLOCKS * 4;
  int c4 = lane*4;
  int hh = lane >> 3;
  // per-wave constants (amortized over ~NN/NW nodes)
  unsigned wpk[4][8];
  #pragma unroll
  for (int cc = 0; cc < 4; ++cc) {
    uint4 a = *(const uint4*)(Wepk + (size_t)(c4+cc)*8);
    uint4 b = *(const uint4*)(Wepk + (size_t)(c4+cc)*8 + 4);
    wpk[cc][0]=a.x; wpk[cc][1]=a.y; wpk[cc][2]=a.z; wpk[cc][3]=a.w;
    wpk[cc][4]=b.x; wpk[cc][5]=b.y; wpk[cc][6]=b.z; wpk[cc][7]=b.w;
  }
  float4 av = *(const float4*)(att + hh*CH + (lane&7)*4);
  float4 b4 = *(const float4*)(bias + c4);

  for (int n = wid; n < NN; n += NW) {
    float4 xr4 = ld_bf4(xrb + (size_t)n*HID + c4);
    float4 xls = ld_bf4(xlb + (size_t)n*HID + c4);

    // self-loop: direct exp (no max subtraction; logits are small)
    float denom; float4 acc;
    {
      const uint4* lp = (const uint4*)(loopea_bf + (size_t)n*ED);
      float ps = edge_logit(wpk, lp[0], lp[1], xls, xr4, av);
      float es = __expf(ps);
      denom = es;
      acc = make_float4(es*xls.x, es*xls.y, es*xls.z, es*xls.w);
    }

    int b0 = row_off[n], b1 = row_off[n+1];
    if (b0 < b1) {
      int last = b1 - 1;
      ushort4 X0, X1, X2, X3;
      uint4 E0, E1, E2, E3, E4, E5, E6, E7;
      {
        int k1 = b0+1 < last ? b0+1 : last;
        int k2 = b0+2 < last ? b0+2 : last;
        int k3 = b0+3 < last ? b0+3 : last;
        X0 = *(const ushort4*)(xlb + (size_t)csr_src[b0]*HID + c4);
        X1 = *(const ushort4*)(xlb + (size_t)csr_src[k1]*HID + c4);
        X2 = *(const ushort4*)(xlb + (size_t)csr_src[k2]*HID + c4);
        X3 = *(const ushort4*)(xlb + (size_t)csr_src[k3]*HID + c4);
        const uint4* ep = (const uint4*)(ea_bf + (size_t)b0*ED);
        E0 = ep[0]; E1 = ep[1]; E2 = ep[2]; E3 = ep[3];
        E4 = ep[4]; E5 = ep[5]; E6 = ep[6]; E7 = ep[7];
      }
      for (int kb = b0; kb < b1; kb += 4) {
        int rem = b1 - kb;
        ushort4 A0 = X0, A1 = X1, A2 = X2, A3 = X3;
        uint4 F0 = E0, F1 = E1, F2 = E2, F3 = E3;
        uint4 F4 = E4, F5 = E5, F6 = E6, F7 = E7;
        if (kb + 4 < b1) {
          int k0 = kb+4;
          int k1 = kb+5 < last ? kb+5 : last;
          int k2 = kb+6 < last ? kb+6 : last;
          int k3 = kb+7 < last ? kb+7 : last;
          X0 = *(const ushort4*)(xlb + (size_t)csr_src[k0]*HID + c4);
          X1 = *(const ushort4*)(xlb + (size_t)csr_src[k1]*HID + c4);
          X2 = *(const ushort4*)(xlb + (size_t)csr_src[k2]*HID + c4);
          X3 = *(const ushort4*)(xlb + (size_t)csr_src[k3]*HID + c4);
          const uint4* ep2 = (const uint4*)(ea_bf + (size_t)(kb+4)*ED);
          E0 = ep2[0]; E1 = ep2[1]; E2 = ep2[2]; E3 = ep2[3];
          E4 = ep2[4]; E5 = ep2[5]; E6 = ep2[6]; E7 = ep2[7];
        }
        float4 xa = bf4(A0), xb_ = bf4(A1), xc = bf4(A2), xd = bf4(A3);
        float p0 = edge_logit(wpk, F0, F1, xa,  xr4, av);
        float p1 = edge_logit(wpk, F2, F3, xb_, xr4, av);
        float p2 = edge_logit(wpk, F4, F5, xc,  xr4, av);
        float p3 = edge_logit(wpk, F6, F7, xd,  xr4, av);
        p1 = (rem > 1) ? p1 : -3.0e38f;   // __expf(-3e38) == 0 -> masked
        p2 = (rem > 2) ? p2 : -3.0e38f;
        p3 = (rem > 3) ? p3 : -3.0e38f;
        float e0 = __expf(p0), e1 = __expf(p1);
        float e2 = __expf(p2), e3 = __expf(p3);
        denom += ((e0+e1) + (e2+e3));
        acc.x += ((e0*xa.x + e1*xb_.x) + (e2*xc.x + e3*xd.x));
        acc.y += ((e0*xa.y + e1*xb_.y) + (e2*xc.y + e3*xd.y));
        acc.z += ((e0*xa.z + e1*xb_.z) + (e2*xc.z + e3*xd.z));
        acc.w += ((e0*xa.w + e1*xb_.w) + (e2*xc.w + e3*xd.w));
      }
    }
    float inv = 1.f / denom;
    float* hp = h + (size_t)n*HID + c4;
    float4 hv = *(const float4*)hp;
    hv.x += acc.x*inv + b4.x;
    hv.y += acc.y*inv + b4.y;
    hv.z += acc.z*inv + b4.z;
    hv.w += acc.w*inv + b4.w;
    *(float4*)hp = hv;
    ushort4 hbv = make_ushort4(f2bf(hv.x), f2bf(hv.y), f2bf(hv.z), f2bf(hv.w));
    *(ushort4*)(hb + (size_t)n*HID + c4) = hbv;
  }
}

// pool partials: block (g,q) sums its slice of graph g's rows; no atomics
__global__ __launch_bounds__(256) void k_pool_part(const float* __restrict__ h,
    const int* __restrict__ batch, float* __restrict__ hgp) {
  int g = blockIdx.x >> 3, q = blockIdx.x & 7;
  int c = threadIdx.x;
  int lo = 0, hi = NN;
  while (lo < hi) { int mid = (lo+hi) >> 1; if (batch[mid] <  g) lo = mid+1; else hi = mid; }
  int n0 = lo;
  lo = 0; hi = NN;
  while (lo < hi) { int mid = (lo+hi) >> 1; if (batch[mid] <= g) lo = mid+1; else hi = mid; }
  int n1 = lo;
  int len = n1 - n0;
  int a = n0 + (int)(( (long long)len *  q   ) / PPG);
  int b = n0 + (int)(( (long long)len * (q+1)) / PPG);
  float acc = 0.f;
  for (int n = a; n < b; ++n) acc += h[(size_t)n*HID + c];
  hgp[(size_t)blockIdx.x*HID + c] = acc;
}

// out = gelu(mean @ W1 + b1) @ W2 + b2 ; one block per graph
__global__ __launch_bounds__(256) void k_mlp(const float* __restrict__ hgp,
    const int* __restrict__ batch,
    const float* __restrict__ W1, const float* __restrict__ b1,
    const float* __restrict__ W2, const float* __restrict__ b2, float* __restrict__ out) {
  __shared__ float row[HID];
  __shared__ float zrow[HID];
  int g = blockIdx.x, c = threadIdx.x;
  int lo = 0, hi = NN;
  while (lo < hi) { int mid = (lo+hi) >> 1; if (batch[mid] <  g) lo = mid+1; else hi = mid; }
  int n0 = lo;
  lo = 0; hi = NN;
  while (lo < hi) { int mid = (lo+hi) >> 1; if (batch[mid] <= g) lo = mid+1; else hi = mid; }
  float cn = (float)(lo - n0); if (cn < 1.f) cn = 1.f;
  float s = 0.f;
  #pragma unroll
  for (int q = 0; q < PPG; ++q) s += hgp[(size_t)(g*PPG + q)*HID + c];
  row[c] = s / cn;
  __syncthreads();
  float acc = b1[c];
  for (int j = 0; j < HID; ++j) acc += row[j] * W1[(size_t)j*HID + c];
  float ge = 0.5f * acc * (1.f + erff(acc * 0.70710678118654752440f));
  zrow[c] = ge;
  __syncthreads();
  float acc2 = b2[c];
  for (int j = 0; j < HID; ++j) acc2 += zrow[j] * W2[(size_t)j*HID + c];
  out[(size_t)g*HID + c] = acc2;
}

extern "C" void kernel_launch(void* const* d_in, const int* in_sizes, int n_in,
                              void* d_out, int out_size, void* d_ws, size_t ws_size,
                              hipStream_t stream) {
  const float* x         = (const float*)d_in[0];
  const int*   edge_index= (const int*)  d_in[1];
  const float* edge_attr = (const float*)d_in[2];
  const int*   batch     = (const int*)  d_in[3];
  const float* node_W    = (const float*)d_in[4];
  const float* node_b    = (const float*)d_in[5];
  const float* edge_W    = (const float*)d_in[6];
  const float* edge_b    = (const float*)d_in[7];
  const float* Wl        = (const float*)d_in[8];
  const float* bl        = (const float*)d_in[9];
  const float* Wr        = (const float*)d_in[10];
  const float* br        = (const float*)d_in[11];
  const float* We        = (const float*)d_in[12];
  const float* att       = (const float*)d_in[13];
  const float* conv_bias = (const float*)d_in[14];
  const float* W1        = (const float*)d_in[15];
  const float* b1        = (const float*)d_in[16];
  const float* W2        = (const float*)d_in[17];
  const float* b2        = (const float*)d_in[18];
  const int* srcp = edge_index;
  const int* dstp = edge_index + NE;

  float* ws = (float*)d_ws;
  float* h          = ws + OFF_H;
  ushort_t* hb      = (ushort_t*)(ws + OFF_HB);
  ushort_t* ea_bf   = (ushort_t*)(ws + OFF_EABF);
  ushort_t* loop_bf = (ushort_t*)(ws + OFF_LOOPBF);
  float* hgp        = ws + OFF_HGP;
  ushort_t* xlb     = (ushort_t*)(ws + OFF_XLB);
  ushort_t* xrb     = (ushort_t*)(ws + OFF_XRB);
  ushort_t* Bt      = (ushort_t*)(ws + OFF_BT);
  unsigned* Wepk    = (unsigned*)(ws + OFF_WEPK);
  int* ib       = (int*)(ws + OFF_INT);
  int* deg      = ib + IOFF_DEG;
  int* row_off  = ib + IOFF_ROWOFF;
  int* cursor   = ib + IOFF_CURSOR;
  int* csr_src  = ib + IOFF_CSRSRC;
  int* csr_eid  = ib + IOFF_CSREID;

  hipMemsetAsync(deg, 0, NN*sizeof(int), stream);
  k_wt<<<(6*HID*HID + 255)/256, 256, 0, stream>>>(Wl, Wr, Bt);
  k_wepk<<<(NL*HID*8 + 255)/256, 256, 0, stream>>>(We, Wepk);
  k_node_embed<<<NN/4, 256, 0, stream>>>(x, node_W, node_b, h, hb);
  k_deg<<<1250, 256, 0, stream>>>(dstp, deg);
  k_scan<<<1, 1024, 0, stream>>>(deg, row_off, cursor);
  k_fill<<<1250, 256, 0, stream>>>(srcp, dstp, cursor, csr_src, csr_eid);
  k_edge_prep<<<(NN*64 + 255)/256, 256, 0, stream>>>(edge_attr, edge_W, edge_b,
      row_off, csr_eid, ea_bf, loop_bf);

  for (int l = 0; l < NL; ++l) {
    k_gemm_bf16<<<(NN + 63)/64, 512, 0, stream>>>(hb, Bt + (size_t)l*2*HID*HID,
        bl + (size_t)l*HID, br + (size_t)l*HID, xlb, xrb, NN);
    k_gat_fused<<<GAT_BLOCKS, 256, 0, stream>>>(xlb, xrb, ea_bf, loop_bf,
        row_off, csr_src, Wepk + (size_t)l*HID*8,
        att + (size_t)l*HEADS*CH, conv_bias + (size_t)l*HID, h, hb);
  }

  k_pool_part<<<NB*PPG, 256, 0, stream>>>(h, batch, hgp);
  k_mlp<<<NB, 256, 0, stream>>>(hgp, batch, W1, b1, W2, b2, (float*)d_out);
}

// Round 16
// 520.890 us; speedup vs baseline: 1.5537x; 1.0554x over previous
//
#include <hip/hip_runtime.h>
#include <math.h>

// ---------------- problem constants ----------------
constexpr int NN   = 20000;          // nodes
constexpr int NE   = 320000;         // edges  (mean in-degree = 16)
constexpr int ND   = 64;             // node dim
constexpr int ED   = 16;             // edge dim
constexpr int HID  = 256;
constexpr int HEADS= 8;
constexpr int CH   = 32;             // channels per head
constexpr int NB   = 16;             // graphs
constexpr int NL   = 3;              // layers
constexpr int PPG  = 8;              // pool partials per graph
constexpr float NEG_SLOPE = 0.2f;

typedef unsigned short ushort_t;
typedef __attribute__((ext_vector_type(8))) short short8v;   // 8 bf16 (4 VGPRs)
typedef __attribute__((ext_vector_type(4))) float f32x4;     // MFMA acc

#if __has_builtin(__builtin_amdgcn_fdot2_f32_bf16)
  #define HAVE_DOT2 1
  typedef __bf16 bf16x2v __attribute__((ext_vector_type(2)));
#endif

// ---------------- workspace layout (float units) ----------------
constexpr size_t OFF_H      = 0;                                // [NN][256] f32
constexpr size_t OFF_HB     = OFF_H      + (size_t)NN*HID;      // [NN][256] bf16
constexpr size_t OFF_EABF   = OFF_HB     + (size_t)NN*HID/2;    // [NE][16] bf16 (CSR order)
constexpr size_t OFF_LOOPBF = OFF_EABF   + (size_t)NE*ED/2;     // [NN][16] bf16
constexpr size_t OFF_HGP    = OFF_LOOPBF + (size_t)NN*ED/2;     // [NB*PPG][256] f32
constexpr size_t OFF_XLB    = OFF_HGP    + (size_t)NB*PPG*HID;  // [NN][256] bf16
constexpr size_t OFF_XRB    = OFF_XLB    + (size_t)NN*HID/2;
constexpr size_t OFF_BT     = OFF_XRB    + (size_t)NN*HID/2;    // [6][256][256] bf16
constexpr size_t OFF_WEPK   = OFF_BT     + (size_t)6*HID*HID/2; // [NL][256][8] bf16-pairs (uint)
constexpr size_t OFF_INT    = OFF_WEPK   + (size_t)NL*HID*8;
// int region (indexed in ints from OFF_INT)
constexpr size_t IOFF_DEG    = 0;
constexpr size_t IOFF_ROWOFF = IOFF_DEG    + NN;
constexpr size_t IOFF_CURSOR = IOFF_ROWOFF + NN + 1;
constexpr size_t IOFF_CSRSRC = IOFF_CURSOR + NN;
constexpr size_t IOFF_CSREID = IOFF_CSRSRC + NE;

// ---------------- helpers ----------------
__device__ __forceinline__ ushort_t f2bf(float f) {            // RNE fp32->bf16
  unsigned u = __float_as_uint(f);
  u += 0x7FFFu + ((u >> 16) & 1u);
  return (ushort_t)(u >> 16);
}
__device__ __forceinline__ float bf2f(ushort_t u) {
  return __uint_as_float(((unsigned)u) << 16);
}
__device__ __forceinline__ float4 ld_bf4(const ushort_t* p) {
  ushort4 u = *(const ushort4*)p;
  return make_float4(bf2f(u.x), bf2f(u.y), bf2f(u.z), bf2f(u.w));
}
__device__ __forceinline__ float4 bf4(ushort4 u) {
  return make_float4(bf2f(u.x), bf2f(u.y), bf2f(u.z), bf2f(u.w));
}

// d = dot(bf16pair w, bf16pair e) + c
__device__ __forceinline__ float dot2bf(unsigned w, unsigned e, float c) {
#ifdef HAVE_DOT2
  return __builtin_amdgcn_fdot2_f32_bf16(__builtin_bit_cast(bf16x2v, w),
                                         __builtin_bit_cast(bf16x2v, e), c, false);
#else
  float w0 = bf2f((ushort_t)(w & 0xffff)), w1 = bf2f((ushort_t)(w >> 16));
  float e0 = bf2f((ushort_t)(e & 0xffff)), e1 = bf2f((ushort_t)(e >> 16));
  return c + w0*e0 + w1*e1;
#endif
}

// one edge: z = xa + xr + ea@We (dot2), lrelu, att-dot, 8-lane head reduce
__device__ __forceinline__ float edge_logit(const unsigned (&wpk)[4][8],
    uint4 ea, uint4 eb, float4 xa, float4 xr4, float4 av) {
  unsigned e[8] = {ea.x, ea.y, ea.z, ea.w, eb.x, eb.y, eb.z, eb.w};
  float z0 = xa.x + xr4.x, z1 = xa.y + xr4.y;
  float z2 = xa.z + xr4.z, z3 = xa.w + xr4.w;
  #pragma unroll
  for (int j = 0; j < 8; ++j) {
    z0 = dot2bf(wpk[0][j], e[j], z0);
    z1 = dot2bf(wpk[1][j], e[j], z1);
    z2 = dot2bf(wpk[2][j], e[j], z2);
    z3 = dot2bf(wpk[3][j], e[j], z3);
  }
  z0 = z0 > 0.f ? z0 : z0*NEG_SLOPE;
  z1 = z1 > 0.f ? z1 : z1*NEG_SLOPE;
  z2 = z2 > 0.f ? z2 : z2*NEG_SLOPE;
  z3 = z3 > 0.f ? z3 : z3*NEG_SLOPE;
  float p = z0*av.x + z1*av.y + z2*av.z + z3*av.w;
  p += __shfl_xor(p, 1);
  p += __shfl_xor(p, 2);
  p += __shfl_xor(p, 4);
  return p;
}

// ---------------- setup kernels ----------------
// merged: bf16-transposed GEMM weights (6*65536 elems) + packed We pairs (NL*2048 elems)
__global__ __launch_bounds__(256) void k_wt(const float* __restrict__ Wl,
    const float* __restrict__ Wr, const float* __restrict__ We,
    ushort_t* __restrict__ Bt, unsigned* __restrict__ Wepk) {
  int i = blockIdx.x*256 + threadIdx.x;
  if (i < 6*HID*HID) {
    int mat = i >> 16, rem = i & 65535;
    int k = rem >> 8, n = rem & 255;
    int l = mat >> 1, z = mat & 1;
    const float* W = (z ? Wr : Wl) + (size_t)l*HID*HID;
    Bt[(size_t)mat*HID*HID + (size_t)n*HID + k] = f2bf(W[(size_t)k*HID + n]);
  } else if (i < 6*HID*HID + NL*HID*8) {
    int j = i - 6*HID*HID;
    int l = j / (HID*8), rem = j % (HID*8);
    int c = rem >> 3, j2 = rem & 7;
    const float* W = We + (size_t)l*ED*HID;
    unsigned lo = f2bf(W[(size_t)(2*j2)*HID + c]);
    unsigned hi = f2bf(W[(size_t)(2*j2+1)*HID + c]);
    Wepk[j] = lo | (hi << 16);
  }
}

// h = x @ node_W + node_b; also writes bf16 mirror hb
__global__ __launch_bounds__(256) void k_node_embed(const float* __restrict__ x,
    const float* __restrict__ W, const float* __restrict__ b,
    float* __restrict__ h, ushort_t* __restrict__ hb) {
  __shared__ float xs[4][ND];
  int n0 = blockIdx.x * 4;
  int tid = threadIdx.x;
  { int r = tid >> 6, j = tid & 63; xs[r][j] = x[(size_t)(n0+r)*ND + j]; }
  __syncthreads();
  int c = tid;
  float a0 = b[c], a1 = b[c], a2 = b[c], a3 = b[c];
  #pragma unroll 8
  for (int j = 0; j < ND; ++j) {
    float w = W[(size_t)j*HID + c];
    a0 += xs[0][j]*w; a1 += xs[1][j]*w; a2 += xs[2][j]*w; a3 += xs[3][j]*w;
  }
  h[(size_t)(n0+0)*HID+c]=a0; h[(size_t)(n0+1)*HID+c]=a1;
  h[(size_t)(n0+2)*HID+c]=a2; h[(size_t)(n0+3)*HID+c]=a3;
  hb[(size_t)(n0+0)*HID+c]=f2bf(a0); hb[(size_t)(n0+1)*HID+c]=f2bf(a1);
  hb[(size_t)(n0+2)*HID+c]=f2bf(a2); hb[(size_t)(n0+3)*HID+c]=f2bf(a3);
}

__global__ __launch_bounds__(256) void k_deg(const int* __restrict__ dst, int* deg) {
  int i = blockIdx.x*256 + threadIdx.x;
  for (; i < NE; i += gridDim.x*256) atomicAdd(&deg[dst[i]], 1);
}

// single-block scan of deg -> row_off (excl prefix) + cursor copy; row_off[NN]=E
__global__ __launch_bounds__(1024) void k_scan(const int* __restrict__ deg,
    int* __restrict__ row_off, int* __restrict__ cursor) {
  __shared__ int sm[1024];
  const int CHK = (NN + 1023) / 1024;   // 20
  int t = threadIdx.x;
  int base = t * CHK;
  int s = 0;
  for (int i = 0; i < CHK; ++i) { int idx = base+i; if (idx < NN) s += deg[idx]; }
  sm[t] = s; __syncthreads();
  for (int off = 1; off < 1024; off <<= 1) {
    int v = (t >= off) ? sm[t-off] : 0;
    __syncthreads();
    sm[t] += v;
    __syncthreads();
  }
  int run = (t == 0) ? 0 : sm[t-1];
  for (int i = 0; i < CHK; ++i) {
    int idx = base+i;
    if (idx < NN) { row_off[idx] = run; cursor[idx] = run; run += deg[idx]; }
  }
  if (t == 1023) row_off[NN] = sm[1023];
}

__global__ __launch_bounds__(256) void k_fill(const int* __restrict__ src, const int* __restrict__ dst,
    int* cursor, int* __restrict__ csr_src, int* __restrict__ csr_eid) {
  int e = blockIdx.x*256 + threadIdx.x;
  for (; e < NE; e += gridDim.x*256) {
    int pos = atomicAdd(&cursor[dst[e]], 1);
    csr_src[pos] = src[e];
    csr_eid[pos] = e;
  }
}

// fused: ea rows (edge_attr @ edge_W + edge_b) in CSR order (bf16) + per-node mean (bf16)
__global__ __launch_bounds__(256) void k_edge_prep(const float* __restrict__ edge_attr,
    const float* __restrict__ edge_W, const float* __restrict__ edge_b,
    const int* __restrict__ row_off, const int* __restrict__ csr_eid,
    ushort_t* __restrict__ ea_bf, ushort_t* __restrict__ loopea_bf) {
  int lane = threadIdx.x & 63;
  int n = (blockIdx.x*256 + threadIdx.x) >> 6;
  if (n >= NN) return;
  int e4 = lane >> 4, c = lane & 15;
  float Wc[16];
  #pragma unroll
  for (int j = 0; j < 16; ++j) Wc[j] = edge_W[j*ED + c];
  float bc = edge_b[c];
  int b0 = row_off[n], b1 = row_off[n+1];
  float sum = 0.f;
  for (int kb = b0; kb < b1; kb += 4) {
    int k = kb + e4;
    bool ok = (k < b1);
    int eid = ok ? csr_eid[k] : 0;
    float avv = ok ? edge_attr[(size_t)eid*ED + c] : 0.f;
    float r = bc;
    #pragma unroll
    for (int j = 0; j < 16; ++j) {
      float aj = __shfl(avv, (e4 << 4) + j);
      r += aj * Wc[j];
    }
    if (ok) { ea_bf[(size_t)k*ED + c] = f2bf(r); sum += r; }
  }
  sum += __shfl_xor(sum, 16);
  sum += __shfl_xor(sum, 32);
  if (lane < 16) {
    int dg = b1 - b0;
    loopea_bf[(size_t)n*ED + c] = f2bf(sum / (float)(dg > 1 ? dg : 1));
  }
}

// ---------------- bf16 MFMA dual GEMM: BOTH matrices in one block ----------------
__global__ __launch_bounds__(512) void k_gemm_bf16(const ushort_t* __restrict__ hb,
    const ushort_t* __restrict__ Bt,
    const float* __restrict__ bias0, const float* __restrict__ bias1,
    ushort_t* __restrict__ C0, ushort_t* __restrict__ C1, int M) {
  __shared__ ushort_t As[64][HID + 8];       // 64 x 264 bf16 = 33.8 KB
  int tid = threadIdx.x;
  int w = tid >> 6;                 // 0..7
  int z = w >> 2;                   // matrix select
  int wsub = w & 3;                 // 64-col group within matrix
  int lane = tid & 63, l15 = lane & 15, kg = lane >> 4;
  int m0 = blockIdx.x * 64;
  const ushort_t* B = Bt + (size_t)z*HID*HID;
  const float* bias = z ? bias1 : bias0;
  ushort_t* C       = z ? C1 : C0;
  // stage full A tile once (shared by both matrices): 8 threads/row x 32 cols
  {
    int r = tid >> 3, cchunk = (tid & 7) * 32;
    int gr = m0 + r; if (gr >= M) gr = M - 1;
    const float4* srcp = (const float4*)(hb + (size_t)gr*HID + cchunk);
    float4 t0 = srcp[0], t1 = srcp[1], t2 = srcp[2], t3 = srcp[3];
    *(float4*)&As[r][cchunk+0]  = t0;
    *(float4*)&As[r][cchunk+8]  = t1;
    *(float4*)&As[r][cchunk+16] = t2;
    *(float4*)&As[r][cchunk+24] = t3;
  }
  f32x4 acc[4][4];
  #pragma unroll
  for (int mi = 0; mi < 4; ++mi)
    #pragma unroll
    for (int ni = 0; ni < 4; ++ni)
      acc[mi][ni] = (f32x4){0.f,0.f,0.f,0.f};
  // B pipeline: prefetch k0=0 fragments while A staging settles
  const ushort_t* Bw = B + (size_t)(wsub*64 + l15)*HID + kg*8;   // + ni*16*HID + k0
  short8v bn[4];
  #pragma unroll
  for (int ni = 0; ni < 4; ++ni)
    bn[ni] = *(const short8v*)(Bw + (size_t)ni*16*HID);
  __syncthreads();
  for (int k0 = 0; k0 < HID; k0 += 32) {
    short8v a[4], b[4];
    #pragma unroll
    for (int ni = 0; ni < 4; ++ni) b[ni] = bn[ni];
    if (k0 + 32 < HID) {
      #pragma unroll
      for (int ni = 0; ni < 4; ++ni)
        bn[ni] = *(const short8v*)(Bw + (size_t)ni*16*HID + k0 + 32);
    }
    #pragma unroll
    for (int mi = 0; mi < 4; ++mi)
      a[mi] = *(const short8v*)&As[mi*16 + l15][k0 + kg*8];
    #pragma unroll
    for (int mi = 0; mi < 4; ++mi)
      #pragma unroll
      for (int ni = 0; ni < 4; ++ni)
        acc[mi][ni] = __builtin_amdgcn_mfma_f32_16x16x32_bf16(a[mi], b[ni], acc[mi][ni], 0, 0, 0);
  }
  // epilogue: D col = lane&15 (n-dim), row = (lane>>4)*4 + r (m-dim)
  #pragma unroll
  for (int ni = 0; ni < 4; ++ni) {
    int col = wsub*64 + ni*16 + l15;
    float bs = bias[col];
    #pragma unroll
    for (int mi = 0; mi < 4; ++mi) {
      #pragma unroll
      for (int r = 0; r < 4; ++r) {
        int row = m0 + mi*16 + kg*4 + r;
        if (row < M) C[(size_t)row*HID + col] = f2bf(acc[mi][ni][r] + bs);
      }
    }
  }
}

// ---- fused GATv2 attention: 1 wave/node, 4-edge unroll, dot2 eemb, X+EA prefetch,
// direct exp accumulation (R13 verbatim — best measured) ----
__global__ __launch_bounds__(256) void k_gat_fused(
    const ushort_t* __restrict__ xlb, const ushort_t* __restrict__ xrb,
    const ushort_t* __restrict__ ea_bf, const ushort_t* __restrict__ loopea_bf,
    const int* __restrict__ row_off, const int* __restrict__ csr_src,
    const unsigned* __restrict__ Wepk, const float* __restrict__ att,
    const float* __restrict__ bias, float* __restrict__ h, ushort_t* __restrict__ hb) {
  int lane = threadIdx.x & 63;
  int n = (blockIdx.x*256 + threadIdx.x) >> 6;
  if (n >= NN) return;
  int c4 = lane*4;
  int hh = lane >> 3;
  // per-lane packed We: 4 channels x 8 bf16-pairs (32 VGPR)
  unsigned wpk[4][8];
  #pragma unroll
  for (int cc = 0; cc < 4; ++cc) {
    uint4 a = *(const uint4*)(Wepk + (size_t)(c4+cc)*8);
    uint4 b = *(const uint4*)(Wepk + (size_t)(c4+cc)*8 + 4);
    wpk[cc][0]=a.x; wpk[cc][1]=a.y; wpk[cc][2]=a.z; wpk[cc][3]=a.w;
    wpk[cc][4]=b.x; wpk[cc][5]=b.y; wpk[cc][6]=b.z; wpk[cc][7]=b.w;
  }
  float4 av  = *(const float4*)(att + hh*CH + (lane&7)*4);
  float4 xr4 = ld_bf4(xrb + (size_t)n*HID + c4);
  float4 xls = ld_bf4(xlb + (size_t)n*HID + c4);

  // self-loop: direct exp (no max subtraction; logits are small)
  float denom; float4 acc;
  {
    const uint4* lp = (const uint4*)(loopea_bf + (size_t)n*ED);
    float ps = edge_logit(wpk, lp[0], lp[1], xls, xr4, av);
    float es = __expf(ps);
    denom = es;
    acc = make_float4(es*xls.x, es*xls.y, es*xls.z, es*xls.w);
  }

  int b0 = row_off[n], b1 = row_off[n+1];
  if (b0 < b1) {
    int last = b1 - 1;
    ushort4 X0, X1, X2, X3;
    uint4 E0, E1, E2, E3, E4, E5, E6, E7;
    {
      int k1 = b0+1 < last ? b0+1 : last;
      int k2 = b0+2 < last ? b0+2 : last;
      int k3 = b0+3 < last ? b0+3 : last;
      X0 = *(const ushort4*)(xlb + (size_t)csr_src[b0]*HID + c4);
      X1 = *(const ushort4*)(xlb + (size_t)csr_src[k1]*HID + c4);
      X2 = *(const ushort4*)(xlb + (size_t)csr_src[k2]*HID + c4);
      X3 = *(const ushort4*)(xlb + (size_t)csr_src[k3]*HID + c4);
      const uint4* ep = (const uint4*)(ea_bf + (size_t)b0*ED);   // reads 4 rows; overrun past b1 is masked
      E0 = ep[0]; E1 = ep[1]; E2 = ep[2]; E3 = ep[3];
      E4 = ep[4]; E5 = ep[5]; E6 = ep[6]; E7 = ep[7];
    }
    for (int kb = b0; kb < b1; kb += 4) {
      int rem = b1 - kb;
      ushort4 A0 = X0, A1 = X1, A2 = X2, A3 = X3;
      uint4 F0 = E0, F1 = E1, F2 = E2, F3 = E3;
      uint4 F4 = E4, F5 = E5, F6 = E6, F7 = E7;
      if (kb + 4 < b1) {
        int k0 = kb+4;
        int k1 = kb+5 < last ? kb+5 : last;
        int k2 = kb+6 < last ? kb+6 : last;
        int k3 = kb+7 < last ? kb+7 : last;
        X0 = *(const ushort4*)(xlb + (size_t)csr_src[k0]*HID + c4);
        X1 = *(const ushort4*)(xlb + (size_t)csr_src[k1]*HID + c4);
        X2 = *(const ushort4*)(xlb + (size_t)csr_src[k2]*HID + c4);
        X3 = *(const ushort4*)(xlb + (size_t)csr_src[k3]*HID + c4);
        const uint4* ep2 = (const uint4*)(ea_bf + (size_t)(kb+4)*ED);
        E0 = ep2[0]; E1 = ep2[1]; E2 = ep2[2]; E3 = ep2[3];
        E4 = ep2[4]; E5 = ep2[5]; E6 = ep2[6]; E7 = ep2[7];
      }
      float4 xa = bf4(A0), xb_ = bf4(A1), xc = bf4(A2), xd = bf4(A3);
      float p0 = edge_logit(wpk, F0, F1, xa,  xr4, av);
      float p1 = edge_logit(wpk, F2, F3, xb_, xr4, av);
      float p2 = edge_logit(wpk, F4, F5, xc,  xr4, av);
      float p3 = edge_logit(wpk, F6, F7, xd,  xr4, av);
      p1 = (rem > 1) ? p1 : -3.0e38f;   // __expf(-3e38) == 0 -> masked
      p2 = (rem > 2) ? p2 : -3.0e38f;
      p3 = (rem > 3) ? p3 : -3.0e38f;
      float e0 = __expf(p0), e1 = __expf(p1);
      float e2 = __expf(p2), e3 = __expf(p3);
      denom += ((e0+e1) + (e2+e3));
      acc.x += ((e0*xa.x + e1*xb_.x) + (e2*xc.x + e3*xd.x));
      acc.y += ((e0*xa.y + e1*xb_.y) + (e2*xc.y + e3*xd.y));
      acc.z += ((e0*xa.z + e1*xb_.z) + (e2*xc.z + e3*xd.z));
      acc.w += ((e0*xa.w + e1*xb_.w) + (e2*xc.w + e3*xd.w));
    }
  }
  float inv = 1.f / denom;
  float* hp = h + (size_t)n*HID + c4;
  float4 hv = *(const float4*)hp;
  float4 b4 = *(const float4*)(bias + c4);
  hv.x += acc.x*inv + b4.x;
  hv.y += acc.y*inv + b4.y;
  hv.z += acc.z*inv + b4.z;
  hv.w += acc.w*inv + b4.w;
  *(float4*)hp = hv;
  ushort4 hbv = make_ushort4(f2bf(hv.x), f2bf(hv.y), f2bf(hv.z), f2bf(hv.w));
  *(ushort4*)(hb + (size_t)n*HID + c4) = hbv;
}

// pool partials: block (g,q) sums its slice of graph g's rows; no atomics
__global__ __launch_bounds__(256) void k_pool_part(const float* __restrict__ h,
    const int* __restrict__ batch, float* __restrict__ hgp) {
  int g = blockIdx.x >> 3, q = blockIdx.x & 7;
  int c = threadIdx.x;
  int lo = 0, hi = NN;
  while (lo < hi) { int mid = (lo+hi) >> 1; if (batch[mid] <  g) lo = mid+1; else hi = mid; }
  int n0 = lo;
  lo = 0; hi = NN;
  while (lo < hi) { int mid = (lo+hi) >> 1; if (batch[mid] <= g) lo = mid+1; else hi = mid; }
  int n1 = lo;
  int len = n1 - n0;
  int a = n0 + (int)(( (long long)len *  q   ) / PPG);
  int b = n0 + (int)(( (long long)len * (q+1)) / PPG);
  float acc = 0.f;
  for (int n = a; n < b; ++n) acc += h[(size_t)n*HID + c];
  hgp[(size_t)blockIdx.x*HID + c] = acc;
}

// out = gelu(mean @ W1 + b1) @ W2 + b2 ; one block per graph
__global__ __launch_bounds__(256) void k_mlp(const float* __restrict__ hgp,
    const int* __restrict__ batch,
    const float* __restrict__ W1, const float* __restrict__ b1,
    const float* __restrict__ W2, const float* __restrict__ b2, float* __restrict__ out) {
  __shared__ float row[HID];
  __shared__ float zrow[HID];
  int g = blockIdx.x, c = threadIdx.x;
  int lo = 0, hi = NN;
  while (lo < hi) { int mid = (lo+hi) >> 1; if (batch[mid] <  g) lo = mid+1; else hi = mid; }
  int n0 = lo;
  lo = 0; hi = NN;
  while (lo < hi) { int mid = (lo+hi) >> 1; if (batch[mid] <= g) lo = mid+1; else hi = mid; }
  float cn = (float)(lo - n0); if (cn < 1.f) cn = 1.f;
  float s = 0.f;
  #pragma unroll
  for (int q = 0; q < PPG; ++q) s += hgp[(size_t)(g*PPG + q)*HID + c];
  row[c] = s / cn;
  __syncthreads();
  float acc = b1[c];
  for (int j = 0; j < HID; ++j) acc += row[j] * W1[(size_t)j*HID + c];
  float ge = 0.5f * acc * (1.f + erff(acc * 0.70710678118654752440f));
  zrow[c] = ge;
  __syncthreads();
  float acc2 = b2[c];
  for (int j = 0; j < HID; ++j) acc2 += zrow[j] * W2[(size_t)j*HID + c];
  out[(size_t)g*HID + c] = acc2;
}

extern "C" void kernel_launch(void* const* d_in, const int* in_sizes, int n_in,
                              void* d_out, int out_size, void* d_ws, size_t ws_size,
                              hipStream_t stream) {
  const float* x         = (const float*)d_in[0];
  const int*   edge_index= (const int*)  d_in[1];
  const float* edge_attr = (const float*)d_in[2];
  const int*   batch     = (const int*)  d_in[3];
  const float* node_W    = (const float*)d_in[4];
  const float* node_b    = (const float*)d_in[5];
  const float* edge_W    = (const float*)d_in[6];
  const float* edge_b    = (const float*)d_in[7];
  const float* Wl        = (const float*)d_in[8];
  const float* bl        = (const float*)d_in[9];
  const float* Wr        = (const float*)d_in[10];
  const float* br        = (const float*)d_in[11];
  const float* We        = (const float*)d_in[12];
  const float* att       = (const float*)d_in[13];
  const float* conv_bias = (const float*)d_in[14];
  const float* W1        = (const float*)d_in[15];
  const float* b1        = (const float*)d_in[16];
  const float* W2        = (const float*)d_in[17];
  const float* b2        = (const float*)d_in[18];
  const int* srcp = edge_index;
  const int* dstp = edge_index + NE;

  float* ws = (float*)d_ws;
  float* h          = ws + OFF_H;
  ushort_t* hb      = (ushort_t*)(ws + OFF_HB);
  ushort_t* ea_bf   = (ushort_t*)(ws + OFF_EABF);
  ushort_t* loop_bf = (ushort_t*)(ws + OFF_LOOPBF);
  float* hgp        = ws + OFF_HGP;
  ushort_t* xlb     = (ushort_t*)(ws + OFF_XLB);
  ushort_t* xrb     = (ushort_t*)(ws + OFF_XRB);
  ushort_t* Bt      = (ushort_t*)(ws + OFF_BT);
  unsigned* Wepk    = (unsigned*)(ws + OFF_WEPK);
  int* ib       = (int*)(ws + OFF_INT);
  int* deg      = ib + IOFF_DEG;
  int* row_off  = ib + IOFF_ROWOFF;
  int* cursor   = ib + IOFF_CURSOR;
  int* csr_src  = ib + IOFF_CSRSRC;
  int* csr_eid  = ib + IOFF_CSREID;

  hipMemsetAsync(deg, 0, NN*sizeof(int), stream);
  k_wt<<<(6*HID*HID + NL*HID*8 + 255)/256, 256, 0, stream>>>(Wl, Wr, We, Bt, Wepk);
  k_node_embed<<<NN/4, 256, 0, stream>>>(x, node_W, node_b, h, hb);
  k_deg<<<1250, 256, 0, stream>>>(dstp, deg);
  k_scan<<<1, 1024, 0, stream>>>(deg, row_off, cursor);
  k_fill<<<1250, 256, 0, stream>>>(srcp, dstp, cursor, csr_src, csr_eid);
  k_edge_prep<<<(NN*64 + 255)/256, 256, 0, stream>>>(edge_attr, edge_W, edge_b,
      row_off, csr_eid, ea_bf, loop_bf);

  for (int l = 0; l < NL; ++l) {
    k_gemm_bf16<<<(NN + 63)/64, 512, 0, stream>>>(hb, Bt + (size_t)l*2*HID*HID,
        bl + (size_t)l*HID, br + (size_t)l*HID, xlb, xrb, NN);
    k_gat_fused<<<(NN*64 + 255)/256, 256, 0, stream>>>(xlb, xrb, ea_bf, loop_bf,
        row_off, csr_src, Wepk + (size_t)l*HID*8,
        att + (size_t)l*HEADS*CH, conv_bias + (size_t)l*HID, h, hb);
  }

  k_pool_part<<<NB*PPG, 256, 0, stream>>>(h, batch, hgp);
  k_mlp<<<NB, 256, 0, stream>>>(hgp, batch, W1, b1, W2, b2, (float*)d_out);
}